// Round 1
// baseline (1025.416 us; speedup 1.0000x reference)
//
#include <hip/hip_runtime.h>
#include <math.h>

namespace {
constexpr int M  = 48;    // fields
constexpr int D  = 128;   // embedding dim
constexpr int H1 = 68;
constexpr int H2 = 32;
constexpr int H3 = 24;
// 1/sqrt(1 + 1e-3) — keras BN inference with fresh moving stats
constexpr float BN_SCALE = 0.9995003746877732f;
}

// Compute one CIN layer for one batch row, entirely in LDS.
//   out[o][d] = sum_k sum_j xk[k][d] * x0[j][d] * W[(k*M+j)*HO + o]
// Thread map: dc = t&31 (d-chunk of 4), oslot = t>>5 (8 slots, 4 o's each).
template<int HK, int HO>
__device__ inline void cin_layer(const float* __restrict__ xk,   // [HK][D] LDS
                                 const float* __restrict__ x0,   // [M][D]  LDS
                                 const float* __restrict__ W,    // [HK*M][HO] global (L2)
                                 float* __restrict__ outk,       // [HO][D] LDS
                                 int t)
{
    const int dc    = t & 31;   // which float4 of the 128 d's
    const int oslot = t >> 5;   // 0..7

    for (int obase = 0; obase < HO; obase += 32) {
        const int o0 = obase + oslot * 4;
        if (o0 < HO) {  // HO % 4 == 0 for all layers, so o0..o0+3 all valid
            float acc[4][4];
            #pragma unroll
            for (int oi = 0; oi < 4; ++oi)
                #pragma unroll
                for (int di = 0; di < 4; ++di) acc[oi][di] = 0.f;

            #pragma unroll 1
            for (int k = 0; k < HK; ++k) {
                const float4 xk4 = ((const float4*)(xk + k * D))[dc];
                const float* wrow = W + (size_t)(k * M) * HO + o0;
                #pragma unroll 4
                for (int j = 0; j < M; ++j) {
                    const float4 x04 = ((const float4*)(x0 + j * D))[dc];
                    const float4 w4  = *(const float4*)(wrow + j * HO);
                    const float p[4]  = { xk4.x * x04.x, xk4.y * x04.y,
                                          xk4.z * x04.z, xk4.w * x04.w };
                    const float wv[4] = { w4.x, w4.y, w4.z, w4.w };
                    #pragma unroll
                    for (int oi = 0; oi < 4; ++oi)
                        #pragma unroll
                        for (int di = 0; di < 4; ++di)
                            acc[oi][di] = fmaf(p[di], wv[oi], acc[oi][di]);
                }
            }
            #pragma unroll
            for (int oi = 0; oi < 4; ++oi) {
                float4 v = make_float4(acc[oi][0], acc[oi][1], acc[oi][2], acc[oi][3]);
                ((float4*)(outk + (size_t)(o0 + oi) * D))[dc] = v;
            }
        }
    }
}

__global__ __launch_bounds__(256, 2)
void dcin_kernel(const int*   __restrict__ x,      // [B][M]
                 const float* __restrict__ emb,    // [M][D]
                 const float* __restrict__ w1,     // [48*48][68]
                 const float* __restrict__ w2,     // [68*48][32]
                 const float* __restrict__ w3,     // [32*48][24]
                 const float* __restrict__ lin_w,  // [48]
                 const float* __restrict__ lin_b,  // [1]
                 const float* __restrict__ fc1_w,  // [6144][64]
                 const float* __restrict__ fc1_b,  // [64]
                 const float* __restrict__ bn1_g, const float* __restrict__ bn1_b,
                 const float* __restrict__ fc2_w,  // [64][48]
                 const float* __restrict__ fc2_b,
                 const float* __restrict__ bn2_g, const float* __restrict__ bn2_b,
                 const float* __restrict__ fc3_w,  // [48][24]
                 const float* __restrict__ fc3_b,
                 const float* __restrict__ bn3_g, const float* __restrict__ bn3_b,
                 const float* __restrict__ out_w,  // [149]
                 const float* __restrict__ out_b,  // [1]
                 float* __restrict__ out)          // [B]
{
    __shared__ float x0s [M  * D];   // 24576 B — original embeddings, kept all phases
    __shared__ float bufA[H1 * D];   // 34816 B — L1 out, L2 in; reused as L3 out
    __shared__ float bufB[H2 * D];   // 16384 B — L2 out, L3 in
    __shared__ float pool[H1 + H2 + H3];
    __shared__ float h1s[64], h2s[48], h3s[24];
    __shared__ float red[256];
    __shared__ int   sx[M];
    __shared__ float slin;

    const int b = blockIdx.x;
    const int t = threadIdx.x;

    if (t < M) sx[t] = x[b * M + t];
    __syncthreads();

    // ---- gather x0 = emb[x[b]] into LDS (float4) ----
    for (int i = t; i < M * D / 4; i += 256) {
        const int j  = i / (D / 4);
        const int dc = i % (D / 4);
        ((float4*)(x0s + j * D))[dc] = ((const float4*)(emb + sx[j] * D))[dc];
    }
    // linear branch: tanh(x_float @ lin_w + lin_b), one thread (needs sx only)
    if (t == 0) {
        float s = lin_b[0];
        for (int j = 0; j < M; ++j) s += (float)sx[j] * lin_w[j];
        slin = tanhf(s);
    }
    __syncthreads();

    // ---- CIN layer 1: xk = x0 (48) -> bufA (68) ----
    cin_layer<M, H1>(x0s, x0s, w1, bufA, t);
    __syncthreads();
    if (t < H1) {
        float s = 0.f;
        for (int dc = 0; dc < D / 4; ++dc) {
            float4 v = ((const float4*)(bufA + t * D))[dc];
            s += v.x + v.y + v.z + v.w;
        }
        pool[t] = s;
    }
    __syncthreads();

    // ---- CIN layer 2: bufA (68) -> bufB (32) ----
    cin_layer<H1, H2>(bufA, x0s, w2, bufB, t);
    __syncthreads();
    if (t < H2) {
        float s = 0.f;
        for (int dc = 0; dc < D / 4; ++dc) {
            float4 v = ((const float4*)(bufB + t * D))[dc];
            s += v.x + v.y + v.z + v.w;
        }
        pool[H1 + t] = s;
    }
    __syncthreads();

    // ---- CIN layer 3: bufB (32) -> bufA reuse (24) ----
    cin_layer<H2, H3>(bufB, x0s, w3, bufA, t);
    __syncthreads();
    if (t < H3) {
        float s = 0.f;
        for (int dc = 0; dc < D / 4; ++dc) {
            float4 v = ((const float4*)(bufA + t * D))[dc];
            s += v.x + v.y + v.z + v.w;
        }
        pool[H1 + H2 + t] = s;
    }

    // ---- deep: fc1 (6144 -> 64), relu, bn1 ----
    {
        const int u = t & 63, part = t >> 6;  // 4 partial sums per output
        float a = 0.f;
        for (int j = part * 12; j < part * 12 + 12; ++j) {
            const float* xr = x0s + j * D;
            const float* wr = fc1_w + (size_t)(j * D) * 64 + u;
            #pragma unroll 4
            for (int d = 0; d < D; ++d)
                a = fmaf(xr[d], wr[(size_t)d * 64], a);
        }
        red[t] = a;
    }
    __syncthreads();
    if (t < 64) {
        float v = red[t] + red[t + 64] + red[t + 128] + red[t + 192] + fc1_b[t];
        v = fmaxf(v, 0.f);
        h1s[t] = bn1_g[t] * v * BN_SCALE + bn1_b[t];
    }
    __syncthreads();

    // ---- fc2 (64 -> 48), tanh, bn2 ----
    if (t < 48) {
        float a = fc2_b[t];
        #pragma unroll 4
        for (int u = 0; u < 64; ++u) a = fmaf(h1s[u], fc2_w[u * 48 + t], a);
        a = tanhf(a);
        h2s[t] = bn2_g[t] * a * BN_SCALE + bn2_b[t];
    }
    __syncthreads();

    // ---- fc3 (48 -> 24), tanh, bn3 ----
    if (t < 24) {
        float a = fc3_b[t];
        #pragma unroll 4
        for (int u = 0; u < 48; ++u) a = fmaf(h2s[u], fc3_w[u * 24 + t], a);
        a = tanhf(a);
        h3s[t] = bn3_g[t] * a * BN_SCALE + bn3_b[t];
    }
    __syncthreads();

    // ---- final: sigmoid(concat([deep(24), linear(1), cin(124)]) @ out_w + out_b) ----
    if (t == 0) {
        float z = out_b[0];
        #pragma unroll 4
        for (int i = 0; i < H3; ++i) z = fmaf(h3s[i], out_w[i], z);
        z = fmaf(slin, out_w[H3], z);
        #pragma unroll 4
        for (int i = 0; i < H1 + H2 + H3; ++i)
            z = fmaf(pool[i], out_w[H3 + 1 + i], z);
        out[b] = 1.f / (1.f + expf(-z));
    }
}

extern "C" void kernel_launch(void* const* d_in, const int* in_sizes, int n_in,
                              void* d_out, int out_size, void* d_ws, size_t ws_size,
                              hipStream_t stream) {
    (void)in_sizes; (void)n_in; (void)d_ws; (void)ws_size; (void)out_size;
    const int*   x     = (const int*)  d_in[0];
    const float* emb   = (const float*)d_in[1];
    const float* w1    = (const float*)d_in[2];
    const float* w2    = (const float*)d_in[3];
    const float* w3    = (const float*)d_in[4];
    const float* lin_w = (const float*)d_in[5];
    const float* lin_b = (const float*)d_in[6];
    const float* fc1_w = (const float*)d_in[7];
    const float* fc1_b = (const float*)d_in[8];
    const float* bn1_g = (const float*)d_in[9];
    const float* bn1_b = (const float*)d_in[10];
    const float* fc2_w = (const float*)d_in[11];
    const float* fc2_b = (const float*)d_in[12];
    const float* bn2_g = (const float*)d_in[13];
    const float* bn2_b = (const float*)d_in[14];
    const float* fc3_w = (const float*)d_in[15];
    const float* fc3_b = (const float*)d_in[16];
    const float* bn3_g = (const float*)d_in[17];
    const float* bn3_b = (const float*)d_in[18];
    const float* out_w = (const float*)d_in[19];
    const float* out_b = (const float*)d_in[20];

    dcin_kernel<<<512, 256, 0, stream>>>(
        x, emb, w1, w2, w3, lin_w, lin_b,
        fc1_w, fc1_b, bn1_g, bn1_b,
        fc2_w, fc2_b, bn2_g, bn2_b,
        fc3_w, fc3_b, bn3_g, bn3_b,
        out_w, out_b, (float*)d_out);
}

// Round 2
// 273.037 us; speedup vs baseline: 3.7556x; 3.7556x over previous
//
#include <hip/hip_runtime.h>
#include <hip/hip_bf16.h>
#include <math.h>

namespace {
constexpr int M  = 48;    // fields
constexpr int D  = 128;   // embedding dim
constexpr int H1 = 68;
constexpr int H2 = 32;
constexpr int H3 = 24;
constexpr int K1 = M  * M;   // 2304
constexpr int K2 = H1 * M;   // 3264
constexpr int K3 = H2 * M;   // 1536
constexpr int HOP1 = 80;     // H1 padded to 5 N-tiles
constexpr int HOP2 = 32;
constexpr int HOP3 = 32;
// ws layout (ushort elements)
constexpr int E1 = (K1 / 8) * HOP1 * 8;   // 184320
constexpr int E2 = (K2 / 8) * HOP2 * 8;   // 104448
constexpr int E3 = (K3 / 8) * HOP3 * 8;   //  49152
constexpr int EF = (M * D) * 64;          // 393216  fc1_w bf16
constexpr int X0S = 52;  // x0T fp32 row stride (float4-aligned, bank-spread)
constexpr int BAS = 70;  // bufA bf16 row stride
constexpr int BBS = 34;  // bufB bf16 row stride
constexpr float BN_SCALE = 0.9995003746877732f;  // 1/sqrt(1+1e-3)
}

typedef __attribute__((ext_vector_type(8))) short short8;
typedef __attribute__((ext_vector_type(4))) float f32x4;

static __device__ __forceinline__ unsigned short f2bs(float f) {
    __hip_bfloat16 h = __float2bfloat16(f);
    return __builtin_bit_cast(unsigned short, h);
}
static __device__ __forceinline__ float bs2f(unsigned short u) {
    return __builtin_bit_cast(float, (unsigned int)u << 16);
}

// ---------------- prep: transpose+convert weights into d_ws (bf16) ----------
// CIN weights stored k8-major: wT[k8][o][i] = W[k8*8+i][o], o < HOP (zero-pad).
// fc1_w stored as straight bf16 copy [6144][64].
__global__ __launch_bounds__(256)
void prep_kernel(const float* __restrict__ w1, const float* __restrict__ w2,
                 const float* __restrict__ w3, const float* __restrict__ fc1w,
                 unsigned short* __restrict__ ws)
{
    const int idx = blockIdx.x * 256 + threadIdx.x;
    if (idx < E1) {
        const int k8 = idx / (HOP1 * 8);
        const int r  = idx - k8 * (HOP1 * 8);
        const int o  = r >> 3, i = r & 7;
        const float v = (o < H1) ? w1[(k8 * 8 + i) * H1 + o] : 0.f;
        ws[idx] = f2bs(v);
    } else if (idx < E1 + E2) {
        const int x = idx - E1;
        const int k8 = x >> 8;        // HOP2*8 = 256
        const int r  = x & 255;
        const int o  = r >> 3, i = r & 7;
        ws[idx] = f2bs(w2[(k8 * 8 + i) * H2 + o]);
    } else if (idx < E1 + E2 + E3) {
        const int x = idx - (E1 + E2);
        const int k8 = x >> 8;
        const int r  = x & 255;
        const int o  = r >> 3, i = r & 7;
        const float v = (o < H3) ? w3[(k8 * 8 + i) * H3 + o] : 0.f;
        ws[idx] = f2bs(v);
    } else if (idx < E1 + E2 + E3 + EF) {
        const int x = idx - (E1 + E2 + E3);
        ws[idx] = f2bs(fc1w[x]);
    }
}

// ---------------- CIN layer via MFMA, one batch row per block ----------------
// C[d][o] = sum_n A[d][n]*W[n][o], n = k*48+j, A[d][n] = xk[d][k]*x0T[d][j].
// Waves split the 8 M-tiles (d) 2 apiece; each quad's 8 A-elems share one k.
template<int KTOT, int HO, int NT, int HOP, bool XKF32, bool WRITEBUF>
__device__ __forceinline__ void cin_mfma(
    const float* __restrict__ x0T,          // [128][X0S] fp32 LDS
    const void*  __restrict__ xksrc,        // fp32(x0T) or bf16 buf LDS
    int xkstride,
    const unsigned short* __restrict__ wt,  // k8-major bf16 global (L2)
    unsigned short* __restrict__ outbuf,    // bf16 LDS or nullptr
    int outstride,
    float* __restrict__ pool, int poff, int t)
{
    const int lane = t & 63, wv = t >> 6;
    const int m = lane & 15, quad = lane >> 4;
    const int d0 = wv * 32 + m;

    f32x4 acc[2][NT];
    #pragma unroll
    for (int mi = 0; mi < 2; ++mi)
        #pragma unroll
        for (int nt = 0; nt < NT; ++nt)
            acc[mi][nt] = (f32x4){0.f, 0.f, 0.f, 0.f};

    for (int ks = 0; ks < KTOT / 32; ++ks) {
        const int n0 = ks * 32 + quad * 8;
        const int t6 = n0 >> 3;
        const int k  = t6 / 6;              // n0 / 48 (uniform per quad)
        const int j0 = (t6 - k * 6) << 3;   // n0 % 48

        short8 av[2];
        #pragma unroll
        for (int mi = 0; mi < 2; ++mi) {
            const int d = d0 + mi * 16;
            float xv;
            if (XKF32) xv = ((const float*)xksrc)[d * xkstride + k];
            else       xv = bs2f(((const unsigned short*)xksrc)[d * xkstride + k]);
            const float4 q0 = *(const float4*)(x0T + d * X0S + j0);
            const float4 q1 = *(const float4*)(x0T + d * X0S + j0 + 4);
            av[mi] = short8{
                (short)f2bs(xv * q0.x), (short)f2bs(xv * q0.y),
                (short)f2bs(xv * q0.z), (short)f2bs(xv * q0.w),
                (short)f2bs(xv * q1.x), (short)f2bs(xv * q1.y),
                (short)f2bs(xv * q1.z), (short)f2bs(xv * q1.w)};
        }

        const int k8 = ks * 4 + quad;
        #pragma unroll
        for (int nt = 0; nt < NT; ++nt) {
            const uint4 braw = *(const uint4*)(wt + (size_t)(k8 * HOP + nt * 16 + m) * 8);
            const short8 bv = __builtin_bit_cast(short8, braw);
            acc[0][nt] = __builtin_amdgcn_mfma_f32_16x16x32_bf16(av[0], bv, acc[0][nt], 0, 0, 0);
            acc[1][nt] = __builtin_amdgcn_mfma_f32_16x16x32_bf16(av[1], bv, acc[1][nt], 0, 0, 0);
        }
    }

    // epilogue: C[d][o] -> next-layer bf16 buf (d-major) + d-pooled sums
    #pragma unroll
    for (int mi = 0; mi < 2; ++mi) {
        #pragma unroll
        for (int nt = 0; nt < NT; ++nt) {
            const int o = nt * 16 + m;
            if (o < HO) {
                const f32x4 a = acc[mi][nt];
                const int dbase = wv * 32 + mi * 16 + quad * 4;
                if (WRITEBUF) {
                    outbuf[(dbase + 0) * outstride + o] = f2bs(a.x);
                    outbuf[(dbase + 1) * outstride + o] = f2bs(a.y);
                    outbuf[(dbase + 2) * outstride + o] = f2bs(a.z);
                    outbuf[(dbase + 3) * outstride + o] = f2bs(a.w);
                }
                atomicAdd(&pool[poff + o], a.x + a.y + a.z + a.w);
            }
        }
    }
}

__global__ __launch_bounds__(256, 2)
void dcin_kernel(const int*   __restrict__ x,
                 const float* __restrict__ emb,
                 const float* __restrict__ lin_w, const float* __restrict__ lin_b,
                 const float* __restrict__ fc1_b,
                 const float* __restrict__ bn1_g, const float* __restrict__ bn1_b,
                 const float* __restrict__ fc2_w, const float* __restrict__ fc2_b,
                 const float* __restrict__ bn2_g, const float* __restrict__ bn2_b,
                 const float* __restrict__ fc3_w, const float* __restrict__ fc3_b,
                 const float* __restrict__ bn3_g, const float* __restrict__ bn3_b,
                 const float* __restrict__ out_w, const float* __restrict__ out_b,
                 const unsigned short* __restrict__ ws,
                 float* __restrict__ out)
{
    __shared__ float          x0T [D * X0S];   // 26624 B, fp32 d-major embeddings
    __shared__ unsigned short bufA[D * BAS];   // 17920 B, L1 out (bf16)
    __shared__ unsigned short bufB[D * BBS];   //  8704 B, L2 out (bf16)
    __shared__ float pool_s[H1 + H2 + H3];     // 124
    __shared__ float red2[512];
    __shared__ float h1s[64], h2s[48], h3s[24];
    __shared__ int   sx[M];
    __shared__ float slin;

    const unsigned short* wt1  = ws;
    const unsigned short* wt2  = ws + E1;
    const unsigned short* wt3  = ws + E1 + E2;
    const unsigned short* fc1b = ws + E1 + E2 + E3;

    const int b = blockIdx.x;
    const int t = threadIdx.x;

    if (t < M) sx[t] = x[b * M + t];
    if (t < H1 + H2 + H3) pool_s[t] = 0.f;
    __syncthreads();

    // gather x0T[d][j] = emb[sx[j]][d]  (coalesced read, transposed LDS write)
    for (int i = t; i < M * (D / 4); i += 256) {
        const int j = i >> 5, dc = i & 31;
        const float4 v = ((const float4*)(emb + (size_t)sx[j] * D))[dc];
        x0T[(dc * 4 + 0) * X0S + j] = v.x;
        x0T[(dc * 4 + 1) * X0S + j] = v.y;
        x0T[(dc * 4 + 2) * X0S + j] = v.z;
        x0T[(dc * 4 + 3) * X0S + j] = v.w;
    }
    if (t == 0) {
        float s = lin_b[0];
        for (int j = 0; j < M; ++j) s += (float)sx[j] * lin_w[j];
        slin = tanhf(s);
    }
    __syncthreads();

    // ---- CIN layers (MFMA) ----
    cin_mfma<K1, H1, 5, HOP1, true,  true >(x0T, x0T,  X0S, wt1, bufA, BAS, pool_s, 0, t);
    __syncthreads();
    cin_mfma<K2, H2, 2, HOP2, false, true >(x0T, bufA, BAS, wt2, bufB, BBS, pool_s, H1, t);
    __syncthreads();
    cin_mfma<K3, H3, 2, HOP3, false, false>(x0T, bufB, BBS, wt3, nullptr, 0, pool_s, H1 + H2, t);

    // ---- deep: fc1 (6144 -> 64) with bf16 weights, relu, bn1 ----
    {
        const int u2 = (t & 31) * 2;     // output pair u2,u2+1
        const int part = t >> 5;         // 8 parts x 6 fields
        float a0 = 0.f, a1 = 0.f;
        for (int j = part * 6; j < part * 6 + 6; ++j) {
            const float* xr = x0T + j;   // x0T[d][j]
            #pragma unroll 4
            for (int d = 0; d < D; ++d) {
                const float xv = xr[d * X0S];
                const unsigned int wp =
                    *(const unsigned int*)(fc1b + (size_t)(j * D + d) * 64 + u2);
                a0 = fmaf(xv, __builtin_bit_cast(float, wp << 16), a0);
                a1 = fmaf(xv, __builtin_bit_cast(float, wp & 0xffff0000u), a1);
            }
        }
        red2[t * 2]     = a0;
        red2[t * 2 + 1] = a1;
    }
    __syncthreads();
    if (t < 64) {
        float v = fc1_b[t];
        #pragma unroll
        for (int p = 0; p < 8; ++p)
            v += red2[(p * 32 + (t >> 1)) * 2 + (t & 1)];
        v = fmaxf(v, 0.f);
        h1s[t] = bn1_g[t] * v * BN_SCALE + bn1_b[t];
    }
    __syncthreads();

    if (t < 48) {
        float a = fc2_b[t];
        #pragma unroll 4
        for (int u = 0; u < 64; ++u) a = fmaf(h1s[u], fc2_w[u * 48 + t], a);
        a = tanhf(a);
        h2s[t] = bn2_g[t] * a * BN_SCALE + bn2_b[t];
    }
    __syncthreads();

    if (t < 24) {
        float a = fc3_b[t];
        #pragma unroll 4
        for (int u = 0; u < 48; ++u) a = fmaf(h2s[u], fc3_w[u * 24 + t], a);
        a = tanhf(a);
        h3s[t] = bn3_g[t] * a * BN_SCALE + bn3_b[t];
    }
    __syncthreads();

    if (t == 0) {
        float z = out_b[0];
        #pragma unroll 4
        for (int i = 0; i < H3; ++i) z = fmaf(h3s[i], out_w[i], z);
        z = fmaf(slin, out_w[H3], z);
        #pragma unroll 4
        for (int i = 0; i < H1 + H2 + H3; ++i)
            z = fmaf(pool_s[i], out_w[H3 + 1 + i], z);
        out[b] = 1.f / (1.f + expf(-z));
    }
}

extern "C" void kernel_launch(void* const* d_in, const int* in_sizes, int n_in,
                              void* d_out, int out_size, void* d_ws, size_t ws_size,
                              hipStream_t stream) {
    (void)in_sizes; (void)n_in; (void)ws_size; (void)out_size;
    const int*   x     = (const int*)  d_in[0];
    const float* emb   = (const float*)d_in[1];
    const float* w1    = (const float*)d_in[2];
    const float* w2    = (const float*)d_in[3];
    const float* w3    = (const float*)d_in[4];
    const float* lin_w = (const float*)d_in[5];
    const float* lin_b = (const float*)d_in[6];
    const float* fc1_w = (const float*)d_in[7];
    const float* fc1_b = (const float*)d_in[8];
    const float* bn1_g = (const float*)d_in[9];
    const float* bn1_b = (const float*)d_in[10];
    const float* fc2_w = (const float*)d_in[11];
    const float* fc2_b = (const float*)d_in[12];
    const float* bn2_g = (const float*)d_in[13];
    const float* bn2_b = (const float*)d_in[14];
    const float* fc3_w = (const float*)d_in[15];
    const float* fc3_b = (const float*)d_in[16];
    const float* bn3_g = (const float*)d_in[17];
    const float* bn3_b = (const float*)d_in[18];
    const float* out_w = (const float*)d_in[19];
    const float* out_b = (const float*)d_in[20];
    unsigned short* ws = (unsigned short*)d_ws;

    const int prep_elems = E1 + E2 + E3 + EF;
    prep_kernel<<<(prep_elems + 255) / 256, 256, 0, stream>>>(w1, w2, w3, fc1_w, ws);

    dcin_kernel<<<512, 256, 0, stream>>>(
        x, emb, lin_w, lin_b,
        fc1_b, bn1_g, bn1_b,
        fc2_w, fc2_b, bn2_g, bn2_b,
        fc3_w, fc3_b, bn3_g, bn3_b,
        out_w, out_b, ws, (float*)d_out);
}

// Round 3
// 233.199 us; speedup vs baseline: 4.3972x; 1.1708x over previous
//
#include <hip/hip_runtime.h>
#include <hip/hip_bf16.h>
#include <math.h>

namespace {
constexpr int M  = 48;    // fields
constexpr int D  = 128;   // embedding dim
constexpr int H1 = 68;
constexpr int H2 = 32;
constexpr int H3 = 24;
constexpr int K1 = M  * M;   // 2304
constexpr int K2 = H1 * M;   // 3264
constexpr int K3 = H2 * M;   // 1536
constexpr int HOP1 = 80;     // H1 padded to 5 N-tiles
constexpr int HOP2 = 32;
constexpr int HOP3 = 32;
// ws layout (ushort elements)
constexpr int E1 = (K1 / 8) * HOP1 * 8;   // 184320
constexpr int E2 = (K2 / 8) * HOP2 * 8;   // 104448
constexpr int E3 = (K3 / 8) * HOP3 * 8;   //  49152
constexpr int EF = (M * D) * 64;          // 393216  fc1_w bf16
constexpr int X0S = 52;  // x0T fp32 row stride (52*4 dw d-stride ≡ 20 mod 32: 2-way max)
constexpr int BAS = 70;  // bufA bf16 row stride (35 dw ≡ 3 mod 32)
constexpr int BBS = 34;  // bufB bf16 row stride (17 dw ≡ 17 mod 32)
constexpr float BN_SCALE = 0.9995003746877732f;  // 1/sqrt(1+1e-3)
}

typedef __attribute__((ext_vector_type(8))) short short8;
typedef __attribute__((ext_vector_type(4))) float f32x4;

static __device__ __forceinline__ unsigned short f2bs(float f) {  // RNE (cold paths)
    __hip_bfloat16 h = __float2bfloat16(f);
    return __builtin_bit_cast(unsigned short, h);
}
static __device__ __forceinline__ float bs2f(unsigned short u) {
    return __builtin_bit_cast(float, (unsigned int)u << 16);
}
// round-half-away bf16 pack of two floats: ~5 VALU ops (hot path)
static __device__ __forceinline__ unsigned int pk2(float a, float b) {
    unsigned int ua = __builtin_bit_cast(unsigned int, a) + 0x8000u;
    unsigned int ub = __builtin_bit_cast(unsigned int, b) + 0x8000u;
    return (ua >> 16) | (ub & 0xffff0000u);
}

// ---------------- prep: transpose+convert weights into d_ws (bf16) ----------
// CIN weights stored k8-major: ws[k8*HOP*8 + o*8 + i] = W[k8*8+i][o] (o<HOP pad 0).
// o-fast thread mapping -> coalesced global reads; scattered writes absorbed by L2.
__global__ __launch_bounds__(256)
void prep_kernel(const float* __restrict__ w1, const float* __restrict__ w2,
                 const float* __restrict__ w3, const float* __restrict__ fc1w,
                 unsigned short* __restrict__ ws)
{
    const int idx = blockIdx.x * 256 + threadIdx.x;
    if (idx < E1) {
        const int k8 = idx / (HOP1 * 8);
        const int r  = idx - k8 * (HOP1 * 8);
        const int i  = r / HOP1;
        const int o  = r - i * HOP1;
        const float v = (o < H1) ? w1[(k8 * 8 + i) * H1 + o] : 0.f;
        ws[k8 * (HOP1 * 8) + o * 8 + i] = f2bs(v);
    } else if (idx < E1 + E2) {
        const int x = idx - E1;
        const int k8 = x >> 8;              // HOP2*8 = 256
        const int r  = x & 255;
        const int i  = r / HOP2;
        const int o  = r - i * HOP2;
        ws[E1 + k8 * (HOP2 * 8) + o * 8 + i] = f2bs(w2[(k8 * 8 + i) * H2 + o]);
    } else if (idx < E1 + E2 + E3) {
        const int x = idx - (E1 + E2);
        const int k8 = x >> 8;
        const int r  = x & 255;
        const int i  = r / HOP3;
        const int o  = r - i * HOP3;
        const float v = (o < H3) ? w3[(k8 * 8 + i) * H3 + o] : 0.f;
        ws[E1 + E2 + k8 * (HOP3 * 8) + o * 8 + i] = f2bs(v);
    } else if (idx < E1 + E2 + E3 + EF) {
        const int x = idx - (E1 + E2 + E3);
        ws[idx] = f2bs(fc1w[x]);            // straight coalesced copy
    }
}

// ---------------- CIN layer via MFMA, one batch row per block ----------------
// C[d][o] = sum_n A[d][n]*W[n][o], n = k*48+j, A[d][n] = xk[d][k]*x0T[d][j].
// 4 waves split the 8 M-tiles (d) 2 apiece. Software-pipelined: A-inputs (LDS)
// and B-frags (L2 global) for kstep+1 are loaded before kstep's MFMAs.
template<int KTOT, int HO, int NT, int HOP, bool XKF32, bool WRITEBUF>
__device__ __forceinline__ void cin_mfma(
    const float* __restrict__ x0T,
    const void*  __restrict__ xksrc, int xkstride,
    const unsigned short* __restrict__ wt,
    unsigned short* __restrict__ outbuf, int outstride,
    float* __restrict__ pool, int poff, int t)
{
    const int lane = t & 63, wv = t >> 6;
    const int m = lane & 15, quad = lane >> 4;
    const int d0 = wv * 32 + m;
    constexpr int KS = KTOT / 32;
    static_assert(KS % 2 == 0, "KS must be even for unroll-2 pipeline");

    f32x4 acc[2][NT];
    #pragma unroll
    for (int mi = 0; mi < 2; ++mi)
        #pragma unroll
        for (int nt = 0; nt < NT; ++nt)
            acc[mi][nt] = (f32x4){0.f, 0.f, 0.f, 0.f};

    float  xvA[2], xvB[2];
    float4 qaA[2], qbA[2], qaB[2], qbB[2];
    uint4  brA[NT], brB[NT];

    auto loadA = [&](int ks, float* xv, float4* qa, float4* qb) {
        const int t6 = ks * 4 + quad;
        const int k  = t6 / 6;
        const int j0 = (t6 - k * 6) << 3;
        #pragma unroll
        for (int mi = 0; mi < 2; ++mi) {
            const int d = d0 + mi * 16;
            if (XKF32) xv[mi] = ((const float*)xksrc)[d * xkstride + k];
            else       xv[mi] = bs2f(((const unsigned short*)xksrc)[d * xkstride + k]);
            qa[mi] = *(const float4*)(x0T + d * X0S + j0);
            qb[mi] = *(const float4*)(x0T + d * X0S + j0 + 4);
        }
    };
    auto loadB = [&](int ks, uint4* br) {
        const int k8 = ks * 4 + quad;
        #pragma unroll
        for (int nt = 0; nt < NT; ++nt)
            br[nt] = *(const uint4*)(wt + (size_t)(k8 * HOP + nt * 16 + m) * 8);
    };
    auto compute = [&](const float* xv, const float4* qa, const float4* qb,
                       const uint4* br) {
        short8 av[2];
        #pragma unroll
        for (int mi = 0; mi < 2; ++mi) {
            const float x = xv[mi];
            uint4 u;
            u.x = pk2(x * qa[mi].x, x * qa[mi].y);
            u.y = pk2(x * qa[mi].z, x * qa[mi].w);
            u.z = pk2(x * qb[mi].x, x * qb[mi].y);
            u.w = pk2(x * qb[mi].z, x * qb[mi].w);
            av[mi] = __builtin_bit_cast(short8, u);
        }
        #pragma unroll
        for (int nt = 0; nt < NT; ++nt) {
            const short8 bv = __builtin_bit_cast(short8, br[nt]);
            acc[0][nt] = __builtin_amdgcn_mfma_f32_16x16x32_bf16(av[0], bv, acc[0][nt], 0, 0, 0);
            acc[1][nt] = __builtin_amdgcn_mfma_f32_16x16x32_bf16(av[1], bv, acc[1][nt], 0, 0, 0);
        }
    };

    loadA(0, xvA, qaA, qbA);
    loadB(0, brA);
    #pragma unroll 1
    for (int ks = 0; ks < KS; ks += 2) {
        loadA(ks + 1, xvB, qaB, qbB);
        loadB(ks + 1, brB);
        compute(xvA, qaA, qbA, brA);
        if (ks + 2 < KS) {
            loadA(ks + 2, xvA, qaA, qbA);
            loadB(ks + 2, brA);
        }
        compute(xvB, qaB, qbB, brB);
    }

    // epilogue: write next-layer bf16 buf (d-major) + quad-reduced pool sums
    #pragma unroll
    for (int mi = 0; mi < 2; ++mi) {
        #pragma unroll
        for (int nt = 0; nt < NT; ++nt) {
            const int o = nt * 16 + m;
            const f32x4 a = acc[mi][nt];
            if (WRITEBUF && o < HO) {
                const int dbase = wv * 32 + mi * 16 + quad * 4;
                outbuf[(dbase + 0) * outstride + o] = f2bs(a.x);
                outbuf[(dbase + 1) * outstride + o] = f2bs(a.y);
                outbuf[(dbase + 2) * outstride + o] = f2bs(a.z);
                outbuf[(dbase + 3) * outstride + o] = f2bs(a.w);
            }
            float s = a.x + a.y + a.z + a.w;
            s += __shfl_xor(s, 16, 64);   // quad ^ 1
            s += __shfl_xor(s, 32, 64);   // quad ^ 2
            if (lane < 16 && o < HO) atomicAdd(&pool[poff + o], s);
        }
    }
}

__global__ __launch_bounds__(256, 2)
void dcin_kernel(const int*   __restrict__ x,
                 const float* __restrict__ emb,
                 const float* __restrict__ lin_w, const float* __restrict__ lin_b,
                 const float* __restrict__ fc1_b,
                 const float* __restrict__ bn1_g, const float* __restrict__ bn1_b,
                 const float* __restrict__ fc2_w, const float* __restrict__ fc2_b,
                 const float* __restrict__ bn2_g, const float* __restrict__ bn2_b,
                 const float* __restrict__ fc3_w, const float* __restrict__ fc3_b,
                 const float* __restrict__ bn3_g, const float* __restrict__ bn3_b,
                 const float* __restrict__ out_w, const float* __restrict__ out_b,
                 const unsigned short* __restrict__ ws,
                 float* __restrict__ out)
{
    __shared__ float          x0T [D * X0S];   // 26624 B, fp32 d-major embeddings
    __shared__ unsigned short bufA[D * BAS];   // 17920 B, L1 out (bf16)
    __shared__ unsigned short bufB[D * BBS];   //  8704 B, L2 out (bf16)
    __shared__ float pool_s[H1 + H2 + H3];
    __shared__ float red2[512];
    __shared__ float h1s[64], h2s[48], h3s[24];
    __shared__ int   sx[M];
    __shared__ float slin;

    const unsigned short* wt1  = ws;
    const unsigned short* wt2  = ws + E1;
    const unsigned short* wt3  = ws + E1 + E2;
    const unsigned short* fc1b = ws + E1 + E2 + E3;

    const int b = blockIdx.x;
    const int t = threadIdx.x;

    if (t < M) sx[t] = x[b * M + t];
    if (t < H1 + H2 + H3) pool_s[t] = 0.f;
    __syncthreads();

    // gather x0T[d][j] = emb[sx[j]][d]; j-fast mapping: LDS writes stride-1 dw
    // (<=2-way bank aliasing, free); reads gather 16B segments served by L1/L2.
    for (int i = t; i < M * (D / 4); i += 256) {
        const int c = i / 48;
        const int j = i - c * 48;
        const float4 v = ((const float4*)(emb + (size_t)sx[j] * D))[c];
        x0T[(4 * c + 0) * X0S + j] = v.x;
        x0T[(4 * c + 1) * X0S + j] = v.y;
        x0T[(4 * c + 2) * X0S + j] = v.z;
        x0T[(4 * c + 3) * X0S + j] = v.w;
    }
    if (t == 0) {
        float s = lin_b[0];
        for (int j = 0; j < M; ++j) s += (float)sx[j] * lin_w[j];
        slin = tanhf(s);
    }
    __syncthreads();

    // ---- CIN layers (MFMA) ----
    cin_mfma<K1, H1, 5, HOP1, true,  true >(x0T, x0T,  X0S, wt1, bufA, BAS, pool_s, 0, t);
    __syncthreads();
    cin_mfma<K2, H2, 2, HOP2, false, true >(x0T, bufA, BAS, wt2, bufB, BBS, pool_s, H1, t);
    __syncthreads();
    cin_mfma<K3, H3, 2, HOP3, false, false>(x0T, bufB, BBS, wt3, nullptr, 0, pool_s, H1 + H2, t);

    // ---- deep: fc1 (6144 -> 64) with bf16 weights, relu, bn1 ----
    {
        const int u2 = (t & 31) * 2;
        const int part = t >> 5;
        float a0 = 0.f, a1 = 0.f;
        for (int j = part * 6; j < part * 6 + 6; ++j) {
            const float* xr = x0T + j;
            #pragma unroll 4
            for (int d = 0; d < D; ++d) {
                const float xv = xr[d * X0S];
                const unsigned int wp =
                    *(const unsigned int*)(fc1b + (size_t)(j * D + d) * 64 + u2);
                a0 = fmaf(xv, __builtin_bit_cast(float, wp << 16), a0);
                a1 = fmaf(xv, __builtin_bit_cast(float, wp & 0xffff0000u), a1);
            }
        }
        red2[t * 2]     = a0;
        red2[t * 2 + 1] = a1;
    }
    __syncthreads();
    if (t < 64) {
        float v = fc1_b[t];
        #pragma unroll
        for (int p = 0; p < 8; ++p)
            v += red2[(p * 32 + (t >> 1)) * 2 + (t & 1)];
        v = fmaxf(v, 0.f);
        h1s[t] = bn1_g[t] * v * BN_SCALE + bn1_b[t];
    }
    __syncthreads();

    if (t < 48) {
        float a = fc2_b[t];
        #pragma unroll 4
        for (int u = 0; u < 64; ++u) a = fmaf(h1s[u], fc2_w[u * 48 + t], a);
        a = tanhf(a);
        h2s[t] = bn2_g[t] * a * BN_SCALE + bn2_b[t];
    }
    __syncthreads();

    if (t < 24) {
        float a = fc3_b[t];
        #pragma unroll 4
        for (int u = 0; u < 48; ++u) a = fmaf(h2s[u], fc3_w[u * 24 + t], a);
        a = tanhf(a);
        h3s[t] = bn3_g[t] * a * BN_SCALE + bn3_b[t];
    }
    __syncthreads();

    if (t == 0) {
        float z = out_b[0];
        #pragma unroll 4
        for (int i = 0; i < H3; ++i) z = fmaf(h3s[i], out_w[i], z);
        z = fmaf(slin, out_w[H3], z);
        #pragma unroll 4
        for (int i = 0; i < H1 + H2 + H3; ++i)
            z = fmaf(pool_s[i], out_w[H3 + 1 + i], z);
        out[b] = 1.f / (1.f + expf(-z));
    }
}

extern "C" void kernel_launch(void* const* d_in, const int* in_sizes, int n_in,
                              void* d_out, int out_size, void* d_ws, size_t ws_size,
                              hipStream_t stream) {
    (void)in_sizes; (void)n_in; (void)ws_size; (void)out_size;
    const int*   x     = (const int*)  d_in[0];
    const float* emb   = (const float*)d_in[1];
    const float* w1    = (const float*)d_in[2];
    const float* w2    = (const float*)d_in[3];
    const float* w3    = (const float*)d_in[4];
    const float* lin_w = (const float*)d_in[5];
    const float* lin_b = (const float*)d_in[6];
    const float* fc1_w = (const float*)d_in[7];
    const float* fc1_b = (const float*)d_in[8];
    const float* bn1_g = (const float*)d_in[9];
    const float* bn1_b = (const float*)d_in[10];
    const float* fc2_w = (const float*)d_in[11];
    const float* fc2_b = (const float*)d_in[12];
    const float* bn2_g = (const float*)d_in[13];
    const float* bn2_b = (const float*)d_in[14];
    const float* fc3_w = (const float*)d_in[15];
    const float* fc3_b = (const float*)d_in[16];
    const float* bn3_g = (const float*)d_in[17];
    const float* bn3_b = (const float*)d_in[18];
    const float* out_w = (const float*)d_in[19];
    const float* out_b = (const float*)d_in[20];
    unsigned short* ws = (unsigned short*)d_ws;

    const int prep_elems = E1 + E2 + E3 + EF;
    prep_kernel<<<(prep_elems + 255) / 256, 256, 0, stream>>>(w1, w2, w3, fc1_w, ws);

    dcin_kernel<<<512, 256, 0, stream>>>(
        x, emb, lin_w, lin_b,
        fc1_b, bn1_g, bn1_b,
        fc2_w, fc2_b, bn2_g, bn2_b,
        fc3_w, fc3_b, bn3_g, bn3_b,
        out_w, out_b, ws, (float*)d_out);
}

// Round 5
// 229.480 us; speedup vs baseline: 4.4684x; 1.0162x over previous
//
#include <hip/hip_runtime.h>
#include <hip/hip_bf16.h>
#include <math.h>

namespace {
constexpr int M  = 48;    // fields
constexpr int D  = 128;   // embedding dim
constexpr int H1 = 68;
constexpr int H2 = 32;
constexpr int H3 = 24;
constexpr int K1 = M  * M;   // 2304
constexpr int K2 = H1 * M;   // 3264
constexpr int K3 = H2 * M;   // 1536
constexpr int HOP1 = 80;     // H1 padded to 5 N-tiles
constexpr int HOP2 = 32;
constexpr int HOP3 = 32;
// ws layout (ushort elements)
constexpr int E1 = (K1 / 8) * HOP1 * 8;   // 184320
constexpr int E2 = (K2 / 8) * HOP2 * 8;   // 104448
constexpr int E3 = (K3 / 8) * HOP3 * 8;   //  49152
constexpr int EF = (M * D) * 64;          // 393216  fc1_w bf16
constexpr int X0S = 52;  // x0T fp32 stride
constexpr int BAS = 69;  // bufA fp32 stride (odd dw -> conflict-free scalar)
constexpr int BBS = 33;  // bufB fp32 stride
constexpr float BN_SCALE = 0.9995003746877732f;  // 1/sqrt(1+1e-3)
// prep thread-space
constexpr int P1 = (K1 / 8) * HOP1;  // 23040
constexpr int P2 = (K2 / 8) * HOP2;  // 13056
constexpr int P3 = (K3 / 8) * HOP3;  //  6144
constexpr int P4 = EF / 8;           // 49152
}

typedef __attribute__((ext_vector_type(8))) short short8;
typedef __attribute__((ext_vector_type(4))) float f32x4;
typedef __attribute__((ext_vector_type(8))) unsigned short us8;

static __device__ __forceinline__ unsigned short f2bs(float f) {  // RNE (cold paths)
    __hip_bfloat16 h = __float2bfloat16(f);
    return __builtin_bit_cast(unsigned short, h);
}
// round-half-away bf16 pack of two floats (R3-proven hot path)
static __device__ __forceinline__ unsigned int pk2(float a, float b) {
    unsigned int ua = __builtin_bit_cast(unsigned int, a) + 0x8000u;
    unsigned int ub = __builtin_bit_cast(unsigned int, b) + 0x8000u;
    return (ua >> 16) | (ub & 0xffff0000u);
}

// ---------------- prep: transpose+convert weights into d_ws (bf16) ----------
// CIN weights k8-major: ws[k8*HOP*8 + o*8 + i] = W[k8*8+i][o] (o<HOP pad 0).
// One thread per (k8,o): 8 coalesced-by-o reads, one 16B store.
__global__ __launch_bounds__(256)
void prep_kernel(const float* __restrict__ w1, const float* __restrict__ w2,
                 const float* __restrict__ w3, const float* __restrict__ fc1w,
                 unsigned short* __restrict__ ws)
{
    const int tid = blockIdx.x * 256 + threadIdx.x;
    us8 v;
    if (tid < P1) {
        const int k8 = tid / HOP1, o = tid - k8 * HOP1;
        #pragma unroll
        for (int i = 0; i < 8; ++i)
            v[i] = (short)((o < H1) ? f2bs(w1[(k8 * 8 + i) * H1 + o]) : 0);
        *(uint4*)(ws + (size_t)k8 * (HOP1 * 8) + o * 8) = __builtin_bit_cast(uint4, v);
    } else if (tid < P1 + P2) {
        const int x = tid - P1;
        const int k8 = x >> 5, o = x & 31;
        #pragma unroll
        for (int i = 0; i < 8; ++i)
            v[i] = (short)f2bs(w2[(k8 * 8 + i) * H2 + o]);
        *(uint4*)(ws + E1 + (size_t)k8 * (HOP2 * 8) + o * 8) = __builtin_bit_cast(uint4, v);
    } else if (tid < P1 + P2 + P3) {
        const int x = tid - (P1 + P2);
        const int k8 = x >> 5, o = x & 31;
        #pragma unroll
        for (int i = 0; i < 8; ++i)
            v[i] = (short)((o < H3) ? f2bs(w3[(k8 * 8 + i) * H3 + o]) : 0);
        *(uint4*)(ws + E1 + E2 + (size_t)k8 * (HOP3 * 8) + o * 8) = __builtin_bit_cast(uint4, v);
    } else if (tid < P1 + P2 + P3 + P4) {
        const int x = tid - (P1 + P2 + P3);
        const float4 a = ((const float4*)fc1w)[x * 2];
        const float4 b = ((const float4*)fc1w)[x * 2 + 1];
        v[0] = (short)f2bs(a.x); v[1] = (short)f2bs(a.y);
        v[2] = (short)f2bs(a.z); v[3] = (short)f2bs(a.w);
        v[4] = (short)f2bs(b.x); v[5] = (short)f2bs(b.y);
        v[6] = (short)f2bs(b.z); v[7] = (short)f2bs(b.w);
        *(uint4*)(ws + E1 + E2 + E3 + (size_t)x * 8) = __builtin_bit_cast(uint4, v);
    }
}

// ---------------- CIN layer via MFMA, one batch row per 512-thread block -----
// C[d][o] = sum_n A[d][n]*W[n][o], n = k*48+j, A[d][n] = xk[d][k]*x0T[d][j].
// 8 waves: pair (w, w+4) shares M-tile group w (32 d's), splits kstep range in
// half -> 4 waves/SIMD with zero duplicated B traffic / A-build VALU.
// Deterministic combine: khalf=0 stores partials, barrier, khalf=1 adds.
template<int KTOT, int HO, int NT, int HOP, bool WRITEBUF>
__device__ __forceinline__ void cin_mfma(
    const float* __restrict__ x0T,
    const float* __restrict__ xksrc, int xkstride,
    const unsigned short* __restrict__ wt,
    float* __restrict__ outbuf, int outstride,
    float* __restrict__ pool, int poff, int t)
{
    const int lane  = t & 63;
    const int w4    = (t >> 6) & 3;   // M-tile group
    const int khalf = t >> 8;         // 0 or 1: K-range half (wave-uniform)
    const int m = lane & 15, quad = lane >> 4;
    const int d0 = w4 * 32 + m;
    constexpr int KS = KTOT / 32;
    constexpr int C0 = (KS / 2 + 1) & ~1;   // even lower-half count
    constexpr int C1 = KS - C0;             // even upper-half count
    static_assert(C0 % 2 == 0 && C1 % 2 == 0, "both K halves must be even");
    const int ks0 = khalf ? C0 : 0;
    const int cnt = khalf ? C1 : C0;

    f32x4 acc[2][NT];
    #pragma unroll
    for (int mi = 0; mi < 2; ++mi)
        #pragma unroll
        for (int nt = 0; nt < NT; ++nt)
            acc[mi][nt] = (f32x4){0.f, 0.f, 0.f, 0.f};

    float  xvA[2], xvB[2];
    float4 qaA[2], qbA[2], qaB[2], qbB[2];
    uint4  brA[NT], brB[NT];

    auto loadA = [&](int ks, float* xv, float4* qa, float4* qb) {
        const int t6 = ks * 4 + quad;
        const int k  = t6 / 6;
        const int j0 = (t6 - k * 6) << 3;
        #pragma unroll
        for (int mi = 0; mi < 2; ++mi) {
            const int d = d0 + mi * 16;
            xv[mi] = xksrc[d * xkstride + k];
            qa[mi] = *(const float4*)(x0T + d * X0S + j0);
            qb[mi] = *(const float4*)(x0T + d * X0S + j0 + 4);
        }
    };
    auto loadB = [&](int ks, uint4* br) {
        const int k8 = ks * 4 + quad;
        #pragma unroll
        for (int nt = 0; nt < NT; ++nt)
            br[nt] = *(const uint4*)(wt + (size_t)(k8 * HOP + nt * 16 + m) * 8);
    };
    auto compute = [&](const float* xv, const float4* qa, const float4* qb,
                       const uint4* br) {
        short8 av[2];
        #pragma unroll
        for (int mi = 0; mi < 2; ++mi) {
            const float x = xv[mi];
            uint4 u;
            u.x = pk2(x * qa[mi].x, x * qa[mi].y);
            u.y = pk2(x * qa[mi].z, x * qa[mi].w);
            u.z = pk2(x * qb[mi].x, x * qb[mi].y);
            u.w = pk2(x * qb[mi].z, x * qb[mi].w);
            av[mi] = __builtin_bit_cast(short8, u);
        }
        #pragma unroll
        for (int nt = 0; nt < NT; ++nt) {
            const short8 bv = __builtin_bit_cast(short8, br[nt]);
            acc[0][nt] = __builtin_amdgcn_mfma_f32_16x16x32_bf16(av[0], bv, acc[0][nt], 0, 0, 0);
            acc[1][nt] = __builtin_amdgcn_mfma_f32_16x16x32_bf16(av[1], bv, acc[1][nt], 0, 0, 0);
        }
    };

    loadA(ks0, xvA, qaA, qbA);
    loadB(ks0, brA);
    #pragma unroll 1
    for (int s = 0; s < cnt; s += 2) {
        const int ks = ks0 + s;
        loadA(ks + 1, xvB, qaB, qbB);
        loadB(ks + 1, brB);
        compute(xvA, qaA, qbA, brA);
        if (s + 2 < cnt) {
            loadA(ks + 2, xvA, qaA, qbA);
            loadB(ks + 2, brA);
        }
        compute(xvB, qaB, qbB, brB);
    }

    // epilogue: pool partials (atomic, R2/R3-proven path) + khalf=0 stores
    #pragma unroll
    for (int mi = 0; mi < 2; ++mi) {
        #pragma unroll
        for (int nt = 0; nt < NT; ++nt) {
            const int o = nt * 16 + m;
            if (o < HO) {
                const f32x4 a = acc[mi][nt];
                if (WRITEBUF && khalf == 0) {
                    const int dbase = w4 * 32 + mi * 16 + quad * 4;
                    outbuf[(dbase + 0) * outstride + o] = a.x;
                    outbuf[(dbase + 1) * outstride + o] = a.y;
                    outbuf[(dbase + 2) * outstride + o] = a.z;
                    outbuf[(dbase + 3) * outstride + o] = a.w;
                }
                float s = a.x + a.y + a.z + a.w;
                s += __shfl_xor(s, 16, 64);
                s += __shfl_xor(s, 32, 64);
                if (lane < 16) atomicAdd(&pool[poff + o], s);
            }
        }
    }
    __syncthreads();   // khalf=0 partials visible
    if (WRITEBUF && khalf == 1) {
        #pragma unroll
        for (int mi = 0; mi < 2; ++mi) {
            #pragma unroll
            for (int nt = 0; nt < NT; ++nt) {
                const int o = nt * 16 + m;
                if (o < HO) {
                    const f32x4 a = acc[mi][nt];
                    const int dbase = w4 * 32 + mi * 16 + quad * 4;
                    outbuf[(dbase + 0) * outstride + o] += a.x;
                    outbuf[(dbase + 1) * outstride + o] += a.y;
                    outbuf[(dbase + 2) * outstride + o] += a.z;
                    outbuf[(dbase + 3) * outstride + o] += a.w;
                }
            }
        }
    }
}

__global__ __launch_bounds__(512, 4)
void dcin_kernel(const int*   __restrict__ x,
                 const float* __restrict__ emb,
                 const float* __restrict__ lin_w, const float* __restrict__ lin_b,
                 const float* __restrict__ fc1_b,
                 const float* __restrict__ bn1_g, const float* __restrict__ bn1_b,
                 const float* __restrict__ fc2_w, const float* __restrict__ fc2_b,
                 const float* __restrict__ bn2_g, const float* __restrict__ bn2_b,
                 const float* __restrict__ fc3_w, const float* __restrict__ fc3_b,
                 const float* __restrict__ bn3_g, const float* __restrict__ bn3_b,
                 const float* __restrict__ out_w, const float* __restrict__ out_b,
                 const unsigned short* __restrict__ ws,
                 float* __restrict__ out)
{
    __shared__ float x0T [D * X0S];               // 26624 B fp32 d-major embeddings
    __shared__ float bufA[D * BAS];               // 35328 B fp32 L1 out
    __shared__ __align__(16) float bufB[D * BBS]; // 16896 B fp32 L2 out (red2 aliases)
    __shared__ float pool_s[H1 + H2 + H3];
    __shared__ float h1s[64], h2s[48], h3s[24];
    __shared__ int   sx[M];
    __shared__ float slin;
    float* const red2 = bufB;                     // 1024 floats, used after layer 3

    const unsigned short* wt1  = ws;
    const unsigned short* wt2  = ws + E1;
    const unsigned short* wt3  = ws + E1 + E2;
    const unsigned short* fc1b = ws + E1 + E2 + E3;

    const int b = blockIdx.x;
    const int t = threadIdx.x;

    if (t < M) sx[t] = x[b * M + t];
    if (t < H1 + H2 + H3) pool_s[t] = 0.f;
    __syncthreads();

    // gather x0T[d][j] = emb[sx[j]][d]; j-fast: stride-1 dw LDS writes
    for (int i = t; i < M * (D / 4); i += 512) {
        const int c = i / 48;
        const int j = i - c * 48;
        const float4 v = ((const float4*)(emb + (size_t)sx[j] * D))[c];
        x0T[(4 * c + 0) * X0S + j] = v.x;
        x0T[(4 * c + 1) * X0S + j] = v.y;
        x0T[(4 * c + 2) * X0S + j] = v.z;
        x0T[(4 * c + 3) * X0S + j] = v.w;
    }
    if (t == 0) {
        float s = lin_b[0];
        for (int j = 0; j < M; ++j) s += (float)sx[j] * lin_w[j];
        slin = tanhf(s);
    }
    __syncthreads();

    // ---- CIN layers (MFMA, K split across wave pairs) ----
    cin_mfma<K1, H1, 5, HOP1, true >(x0T, x0T,  X0S, wt1, bufA, BAS, pool_s, 0, t);
    __syncthreads();
    cin_mfma<K2, H2, 2, HOP2, true >(x0T, bufA, BAS, wt2, bufB, BBS, pool_s, H1, t);
    __syncthreads();
    cin_mfma<K3, H3, 2, HOP3, false>(x0T, bufB, BBS, wt3, nullptr, 0, pool_s, H1 + H2, t);
    __syncthreads();   // bufB (aliased by red2) must be dead before fc1 writes

    // ---- deep: fc1 (6144 -> 64) with bf16 weights, relu, bn1 ----
    {
        const int u2 = (t & 31) * 2;
        const int part = t >> 5;          // 16 parts x 3 fields
        float a0 = 0.f, a1 = 0.f;
        for (int j = part * 3; j < part * 3 + 3; ++j) {
            const float* xr = x0T + j;
            #pragma unroll 4
            for (int d = 0; d < D; ++d) {
                const float xv = xr[d * X0S];
                const unsigned int wp =
                    *(const unsigned int*)(fc1b + (size_t)(j * D + d) * 64 + u2);
                a0 = fmaf(xv, __builtin_bit_cast(float, wp << 16), a0);
                a1 = fmaf(xv, __builtin_bit_cast(float, wp & 0xffff0000u), a1);
            }
        }
        red2[t * 2]     = a0;
        red2[t * 2 + 1] = a1;
    }
    __syncthreads();
    if (t < 64) {
        float v = fc1_b[t];
        #pragma unroll
        for (int p = 0; p < 16; ++p)
            v += red2[(p * 32 + (t >> 1)) * 2 + (t & 1)];
        v = fmaxf(v, 0.f);
        h1s[t] = bn1_g[t] * v * BN_SCALE + bn1_b[t];
    }
    __syncthreads();

    if (t < 48) {
        float a = fc2_b[t];
        #pragma unroll 4
        for (int u = 0; u < 64; ++u) a = fmaf(h1s[u], fc2_w[u * 48 + t], a);
        a = tanhf(a);
        h2s[t] = bn2_g[t] * a * BN_SCALE + bn2_b[t];
    }
    __syncthreads();

    if (t < 24) {
        float a = fc3_b[t];
        #pragma unroll 4
        for (int u = 0; u < 48; ++u) a = fmaf(h2s[u], fc3_w[u * 24 + t], a);
        a = tanhf(a);
        h3s[t] = bn3_g[t] * a * BN_SCALE + bn3_b[t];
    }
    __syncthreads();

    if (t == 0) {
        float z = out_b[0];
        #pragma unroll 4
        for (int i = 0; i < H3; ++i) z = fmaf(h3s[i], out_w[i], z);
        z = fmaf(slin, out_w[H3], z);
        #pragma unroll 4
        for (int i = 0; i < H1 + H2 + H3; ++i)
            z = fmaf(pool_s[i], out_w[H3 + 1 + i], z);
        out[b] = 1.f / (1.f + expf(-z));
    }
}

extern "C" void kernel_launch(void* const* d_in, const int* in_sizes, int n_in,
                              void* d_out, int out_size, void* d_ws, size_t ws_size,
                              hipStream_t stream) {
    (void)in_sizes; (void)n_in; (void)ws_size; (void)out_size;
    const int*   x     = (const int*)  d_in[0];
    const float* emb   = (const float*)d_in[1];
    const float* w1    = (const float*)d_in[2];
    const float* w2    = (const float*)d_in[3];
    const float* w3    = (const float*)d_in[4];
    const float* lin_w = (const float*)d_in[5];
    const float* lin_b = (const float*)d_in[6];
    const float* fc1_w = (const float*)d_in[7];
    const float* fc1_b = (const float*)d_in[8];
    const float* bn1_g = (const float*)d_in[9];
    const float* bn1_b = (const float*)d_in[10];
    const float* fc2_w = (const float*)d_in[11];
    const float* fc2_b = (const float*)d_in[12];
    const float* bn2_g = (const float*)d_in[13];
    const float* bn2_b = (const float*)d_in[14];
    const float* fc3_w = (const float*)d_in[15];
    const float* fc3_b = (const float*)d_in[16];
    const float* bn3_g = (const float*)d_in[17];
    const float* bn3_b = (const float*)d_in[18];
    const float* out_w = (const float*)d_in[19];
    const float* out_b = (const float*)d_in[20];
    unsigned short* ws = (unsigned short*)d_ws;

    const int prep_threads = P1 + P2 + P3 + P4;
    prep_kernel<<<(prep_threads + 255) / 256, 256, 0, stream>>>(w1, w2, w3, fc1_w, ws);

    dcin_kernel<<<512, 512, 0, stream>>>(
        x, emb, lin_w, lin_b,
        fc1_b, bn1_g, bn1_b,
        fc2_w, fc2_b, bn2_g, bn2_b,
        fc3_w, fc3_b, bn3_g, bn3_b,
        out_w, out_b, ws, (float*)d_out);
}